// Round 1
// baseline (89.647 us; speedup 1.0000x reference)
//
#include <hip/hip_runtime.h>

// Quanv2d: 4-qubit circuit per 2x2 patch. Weights are patch-independent, so the
// whole circuit reduces to out_q = psi0^T * Re(U^dag Z_q U) * psi0 with psi0 a
// real product state. Per-qubit factorization collapses that to an
// 81-coefficient tensor contraction: out_q = sum_a C_q[a] * prod_q u_q[a_q],
// u_q = (v0^2, v0*v1, v1^2), v0 = cos(ang/2 + pi/4), v1 = sin(ang/2 + pi/4).

static __device__ __forceinline__ int bit_of(int m, int q) { return (m >> (3 - q)) & 1; }

// One block. Lanes 0..15 evolve basis state j -> column j of U (2 layers:
// fused CRZ diagonal, then RY per wire). Then all 256 lanes compute one
// M_q[j][k] entry each and fold it into the 81x4 coefficient tensor C.
__global__ __launch_bounds__(256) void quanv_setup(const float* __restrict__ w,
                                                   float* __restrict__ C) {
    __shared__ float Ur[16][16], Ui[16][16];
    __shared__ float Cs[324];
    const int tid = threadIdx.x;
    for (int i0 = tid; i0 < 324; i0 += 256) Cs[i0] = 0.f;

    if (tid < 16) {
        float sr[16], si[16];
        for (int m = 0; m < 16; ++m) { sr[m] = (m == tid) ? 1.f : 0.f; si[m] = 0.f; }
        for (int layer = 0; layer < 2; ++layer) {
            float phi[4], ry[4];
            for (int q = 0; q < 4; ++q) { phi[q] = w[layer * 8 + q]; ry[q] = w[layer * 8 + 4 + q]; }
            // fused CRZ diagonal: CRZ(phi) on (control=i, target=(i+1)%4)
            for (int m = 0; m < 16; ++m) {
                float th = 0.f;
                for (int q = 0; q < 4; ++q)
                    if (bit_of(m, q)) th += phi[q] * (bit_of(m, (q + 1) & 3) ? 0.5f : -0.5f);
                float cs = cosf(th), sn = sinf(th);
                float r  = sr[m] * cs - si[m] * sn;
                float ii = sr[m] * sn + si[m] * cs;
                sr[m] = r; si[m] = ii;
            }
            // RY(w[layer,4+q]) on wire q: new0 = ct*old0 - st*old1; new1 = st*old0 + ct*old1
            for (int q = 0; q < 4; ++q) {
                float t = ry[q] * 0.5f;
                float ct = cosf(t), st = sinf(t);
                int stride = 8 >> q;  // wire q is bit (3-q)
                for (int m = 0; m < 16; ++m) {
                    if (m & stride) continue;
                    int m1 = m + stride;
                    float r0 = sr[m], r1 = sr[m1];
                    float i0 = si[m], i1 = si[m1];
                    sr[m]  = ct * r0 - st * r1;  sr[m1] = st * r0 + ct * r1;
                    si[m]  = ct * i0 - st * i1;  si[m1] = st * i0 + ct * i1;
                }
            }
        }
        for (int m = 0; m < 16; ++m) { Ur[m][tid] = sr[m]; Ui[m][tid] = si[m]; }
    }
    __syncthreads();

    {
        // M_q[j][k] = sum_m Z_q[m] * (Ur[m][j]Ur[m][k] + Ui[m][j]Ui[m][k]); psi0 real
        const int j = tid >> 4, k = tid & 15;
        float a0 = 0.f, a1 = 0.f, a2 = 0.f, a3 = 0.f;
        for (int m = 0; m < 16; ++m) {
            float s = Ur[m][j] * Ur[m][k] + Ui[m][j] * Ui[m][k];
            a0 += bit_of(m, 0) ? -s : s;
            a1 += bit_of(m, 1) ? -s : s;
            a2 += bit_of(m, 2) ? -s : s;
            a3 += bit_of(m, 3) ? -s : s;
        }
        // symmetric per-qubit pattern: a_q = j_q + k_q in {0,1,2}
        int bin = 0;
        for (int q = 0; q < 4; ++q) bin = bin * 3 + bit_of(j, q) + bit_of(k, q);
        atomicAdd(&Cs[bin * 4 + 0], a0);
        atomicAdd(&Cs[bin * 4 + 1], a1);
        atomicAdd(&Cs[bin * 4 + 2], a2);
        atomicAdd(&Cs[bin * 4 + 3], a3);
    }
    __syncthreads();
    for (int i0 = tid; i0 < 324; i0 += 256) C[i0] = Cs[i0];
}

// One thread per patch. x viewed as float2 so each 2-angle row pair is one
// coalesced 8B load. C accesses are wave-uniform -> scalar loads (SGPR
// operands in the FMAs), no LDS.
__global__ __launch_bounds__(256) void quanv_main(const float2* __restrict__ x2,
                                                  const float* __restrict__ C,
                                                  float4* __restrict__ out) {
    const int tid = blockIdx.x * 256 + threadIdx.x;
    const int b = tid >> 12;          // 4096 patches per image
    const int p = tid & 4095;
    const int pi = p >> 6, pj = p & 63;
    const float2* row = x2 + (size_t)b * 8192 + (size_t)(2 * pi) * 64 + pj;
    float2 a01 = row[0];    // x[b, 2i, 2j], x[b, 2i, 2j+1]
    float2 a23 = row[64];   // x[b, 2i+1, 2j], x[b, 2i+1, 2j+1]

    float ang[4] = {a01.x, a01.y, a23.x, a23.y};
    float u[4][3];
#pragma unroll
    for (int q = 0; q < 4; ++q) {
        // (c - s)/sqrt2 = cos(a/2 + pi/4), (c + s)/sqrt2 = sin(a/2 + pi/4)
        float t = ang[q] * 0.5f + 0.78539816339744831f;
        float s, c;
        __sincosf(t, &s, &c);
        u[q][0] = c * c; u[q][1] = c * s; u[q][2] = s * s;
    }

    float w012[27];
#pragma unroll
    for (int a0 = 0; a0 < 3; ++a0)
#pragma unroll
        for (int a1 = 0; a1 < 3; ++a1) {
            float w01 = u[0][a0] * u[1][a1];
#pragma unroll
            for (int a2 = 0; a2 < 3; ++a2)
                w012[(a0 * 3 + a1) * 3 + a2] = w01 * u[2][a2];
        }

    float acc0 = 0.f, acc1 = 0.f, acc2 = 0.f, acc3 = 0.f;
#pragma unroll
    for (int a = 0; a < 27; ++a) {
        float t0 = w012[a] * u[3][0];
        float t1 = w012[a] * u[3][1];
        float t2 = w012[a] * u[3][2];
        const float* cb = C + a * 12;  // bin = a*3 + a3, layout C[bin*4 + q]
        acc0 += cb[0] * t0 + cb[4] * t1 + cb[8]  * t2;
        acc1 += cb[1] * t0 + cb[5] * t1 + cb[9]  * t2;
        acc2 += cb[2] * t0 + cb[6] * t1 + cb[10] * t2;
        acc3 += cb[3] * t0 + cb[7] * t1 + cb[11] * t2;
    }
    out[tid] = make_float4(acc0, acc1, acc2, acc3);
}

extern "C" void kernel_launch(void* const* d_in, const int* in_sizes, int n_in,
                              void* d_out, int out_size, void* d_ws, size_t ws_size,
                              hipStream_t stream) {
    const float* x = (const float*)d_in[0];
    const float* w = (const float*)d_in[1];
    float* C = (float*)d_ws;            // 324 floats of scratch
    float4* outv = (float4*)d_out;

    quanv_setup<<<1, 256, 0, stream>>>(w, C);

    const int n_patches = in_sizes[0] / 4;       // B * 64 * 64
    quanv_main<<<n_patches / 256, 256, 0, stream>>>((const float2*)x, C, outv);
}

// Round 2
// 87.464 us; speedup vs baseline: 1.0250x; 1.0250x over previous
//
#include <hip/hip_runtime.h>

// Quanv2d: 4-qubit circuit per 2x2 patch. Weights are patch-independent, so
// the circuit reduces to out_q = psi0^T Re(U^dag Z_q U) psi0 with psi0 a real
// product state. Per-qubit factorization -> 81-coeff tensor contraction.
// Round 2: basis change u_q = A . (1, sin a, cos a) folded into the coeff
// tensor at setup, so the main kernel needs only 8 muls + 320 FMAs per patch
// (b[0] == 1 makes one product level free) and sincos acts on `ang` directly.

static __device__ __forceinline__ int bit_of(int m, int q) { return (m >> (3 - q)) & 1; }

// One block. Lanes 0..15 evolve basis state j -> column j of U (2 layers:
// fused CRZ diagonal, then RY per wire). All 256 lanes then compute one
// M_q[j][k] entry, fold into the 81x4 tensor C, and finally 4 axis sweeps
// apply the (u -> trig basis) transform A per qubit. Output layout:
// D[bin*4 + q], bin = ((b0*3+b1)*3+b2)*3+b3 over trig-basis digits.
__global__ __launch_bounds__(256) void quanv_setup(const float* __restrict__ w,
                                                   float* __restrict__ Dout) {
    __shared__ float Ur[16][16], Ui[16][16];
    __shared__ float Cs[324], Ts[324];
    const int tid = threadIdx.x;
    for (int i0 = tid; i0 < 324; i0 += 256) Cs[i0] = 0.f;

    if (tid < 16) {
        float sr[16], si[16];
        for (int m = 0; m < 16; ++m) { sr[m] = (m == tid) ? 1.f : 0.f; si[m] = 0.f; }
        for (int layer = 0; layer < 2; ++layer) {
            float phi[4], ry[4];
            for (int q = 0; q < 4; ++q) { phi[q] = w[layer * 8 + q]; ry[q] = w[layer * 8 + 4 + q]; }
            // fused CRZ diagonal: CRZ(phi) on (control=i, target=(i+1)%4)
            for (int m = 0; m < 16; ++m) {
                float th = 0.f;
                for (int q = 0; q < 4; ++q)
                    if (bit_of(m, q)) th += phi[q] * (bit_of(m, (q + 1) & 3) ? 0.5f : -0.5f);
                float cs = cosf(th), sn = sinf(th);
                float r  = sr[m] * cs - si[m] * sn;
                float ii = sr[m] * sn + si[m] * cs;
                sr[m] = r; si[m] = ii;
            }
            // RY on wire q
            for (int q = 0; q < 4; ++q) {
                float t = ry[q] * 0.5f;
                float ct = cosf(t), st = sinf(t);
                int stride = 8 >> q;  // wire q is bit (3-q)
                for (int m = 0; m < 16; ++m) {
                    if (m & stride) continue;
                    int m1 = m + stride;
                    float r0 = sr[m], r1 = sr[m1];
                    float i0 = si[m], i1 = si[m1];
                    sr[m]  = ct * r0 - st * r1;  sr[m1] = st * r0 + ct * r1;
                    si[m]  = ct * i0 - st * i1;  si[m1] = st * i0 + ct * i1;
                }
            }
        }
        for (int m = 0; m < 16; ++m) { Ur[m][tid] = sr[m]; Ui[m][tid] = si[m]; }
    }
    __syncthreads();

    {
        // M_q[j][k] = sum_m Z_q[m] (Ur[m][j]Ur[m][k] + Ui[m][j]Ui[m][k])
        const int j = tid >> 4, k = tid & 15;
        float a0 = 0.f, a1 = 0.f, a2 = 0.f, a3 = 0.f;
        for (int m = 0; m < 16; ++m) {
            float s = Ur[m][j] * Ur[m][k] + Ui[m][j] * Ui[m][k];
            a0 += bit_of(m, 0) ? -s : s;
            a1 += bit_of(m, 1) ? -s : s;
            a2 += bit_of(m, 2) ? -s : s;
            a3 += bit_of(m, 3) ? -s : s;
        }
        int bin = 0;
        for (int q = 0; q < 4; ++q) bin = bin * 3 + bit_of(j, q) + bit_of(k, q);
        atomicAdd(&Cs[bin * 4 + 0], a0);
        atomicAdd(&Cs[bin * 4 + 1], a1);
        atomicAdd(&Cs[bin * 4 + 2], a2);
        atomicAdd(&Cs[bin * 4 + 3], a3);
    }
    __syncthreads();

    // Basis change per qubit axis: D[b] = sum_a A[a][b] C[a], with
    // u0=(1-s)/2, u1=c/2, u2=(1+s)/2 => A rows: a0=(.5,-.5,0) a1=(0,0,.5) a2=(.5,.5,0)
    // sweep j transforms base-3 digit j (place value 27,9,3,1); ping-pong Cs<->Ts
#pragma unroll
    for (int j = 0; j < 4; ++j) {
        const int pv = (j == 0) ? 27 : (j == 1) ? 9 : (j == 2) ? 3 : 1;
        const float* src = (j & 1) ? Ts : Cs;
        float*       dst = (j & 1) ? Cs : Ts;
        for (int e = tid; e < 324; e += 256) {
            int bin = e >> 2, qo = e & 3;
            int d = (bin / pv) % 3;
            int base = bin - d * pv;
            float i0 = src[(base         ) * 4 + qo];
            float i1 = src[(base +     pv) * 4 + qo];
            float i2 = src[(base + 2 * pv) * 4 + qo];
            dst[e] = (d == 0) ? 0.5f * (i0 + i2)
                   : (d == 1) ? 0.5f * (i2 - i0)
                              : 0.5f * i1;
        }
        __syncthreads();
    }
    for (int i0 = tid; i0 < 324; i0 += 256) Dout[i0] = Cs[i0];  // after 4 sweeps result is back in Cs
}

// One thread per patch. D accesses are wave-uniform -> scalar loads feeding
// v_fma_f32 with an SGPR operand. Inner contraction: two-level Horner over
// (b23, b01) with b[0]==1 levels free: 8 muls + 320 FMAs.
__global__ __launch_bounds__(256) void quanv_main(const float2* __restrict__ x2,
                                                  const float* __restrict__ D,
                                                  float4* __restrict__ out) {
    const int tid = blockIdx.x * 256 + threadIdx.x;
    const int b = tid >> 12;          // 4096 patches per image
    const int p = tid & 4095;
    const int pi = p >> 6, pj = p & 63;
    const float2* row = x2 + (size_t)b * 8192 + (size_t)(2 * pi) * 64 + pj;
    float2 a01 = row[0];    // x[b, 2i, 2j], x[b, 2i, 2j+1]
    float2 a23 = row[64];   // x[b, 2i+1, 2j], x[b, 2i+1, 2j+1]

    float s0, c0, s1, c1, s2, c2, s3, c3;
    __sincosf(a01.x, &s0, &c0);
    __sincosf(a01.y, &s1, &c1);
    __sincosf(a23.x, &s2, &c2);
    __sincosf(a23.y, &s3, &c3);

    // rank-1 products in the (1, sin, cos) basis; index = b_hi*3 + b_lo
    float P01[9], P23[9];
    P01[1] = s1;      P01[2] = c1;      P01[3] = s0;      P01[6] = c0;
    P01[4] = s0 * s1; P01[5] = s0 * c1; P01[7] = c0 * s1; P01[8] = c0 * c1;
    P23[1] = s3;      P23[2] = c3;      P23[3] = s2;      P23[6] = c2;
    P23[4] = s2 * s3; P23[5] = s2 * c3; P23[7] = c2 * s3; P23[8] = c2 * c3;

    float o0, o1, o2, o3;
#pragma unroll
    for (int b01 = 0; b01 < 9; ++b01) {
        const float* Db = D + b01 * 36;              // D[(b01*9 + b23)*4 + q]
        float g0 = Db[0], g1 = Db[1], g2 = Db[2], g3 = Db[3];  // b23 = 0 term (P23[0]==1)
#pragma unroll
        for (int b23 = 1; b23 < 9; ++b23) {
            float pq = P23[b23];
            g0 = fmaf(Db[b23 * 4 + 0], pq, g0);
            g1 = fmaf(Db[b23 * 4 + 1], pq, g1);
            g2 = fmaf(Db[b23 * 4 + 2], pq, g2);
            g3 = fmaf(Db[b23 * 4 + 3], pq, g3);
        }
        if (b01 == 0) { o0 = g0; o1 = g1; o2 = g2; o3 = g3; }  // P01[0]==1
        else {
            float pp = P01[b01];
            o0 = fmaf(g0, pp, o0); o1 = fmaf(g1, pp, o1);
            o2 = fmaf(g2, pp, o2); o3 = fmaf(g3, pp, o3);
        }
    }
    out[tid] = make_float4(o0, o1, o2, o3);
}

extern "C" void kernel_launch(void* const* d_in, const int* in_sizes, int n_in,
                              void* d_out, int out_size, void* d_ws, size_t ws_size,
                              hipStream_t stream) {
    const float* x = (const float*)d_in[0];
    const float* w = (const float*)d_in[1];
    float* Dt = (float*)d_ws;            // 324 floats of scratch
    float4* outv = (float4*)d_out;

    quanv_setup<<<1, 256, 0, stream>>>(w, Dt);

    const int n_patches = in_sizes[0] / 4;       // B * 64 * 64
    quanv_main<<<n_patches / 256, 256, 0, stream>>>((const float2*)x, Dt, outv);
}